// Round 1
// baseline (64.007 us; speedup 1.0000x reference)
//
#include <hip/hip_runtime.h>

// Problem constants (fixed by setup_inputs)
constexpr int T_TASKS = 256;
constexpr int NQ      = 300;
constexpr int NS      = 25;
constexpr int D       = 640;
constexpr int NWAY    = 5;
constexpr float LAMBDA_REG = 50.0f;

constexpr int SP  = D + 4;        // padded LDS row stride (floats), 16B-aligned
constexpr int AC  = NS + NWAY;    // augmented columns = 30
constexpr int QPB = 60;           // queries per block in logits kernel
constexpr int CHUNKS = NQ / QPB;  // 5

// ---------------------------------------------------------------------------
// Kernel 1: per-task ridge solve.
//   K = S S^T + lambda I (25x25, SPD)
//   X = 2 K^{-1} onehot(labels)         (25x5)
//   Wmat[t][w][d] = sum_s S[s][d] X[s][w]   (5x640) -> workspace
// ---------------------------------------------------------------------------
__global__ __launch_bounds__(256) void ridge_solve_kernel(
    const float* __restrict__ support,   // (T, NS, D)
    const int*   __restrict__ labels,    // (T, NS)
    float*       __restrict__ wmat)      // (T, NWAY, D)
{
    __shared__ __align__(16) float sS[NS * SP];   // 25*644*4 = 64,400 B
    __shared__ float aug[NS][32];                 // 25 x 30 augmented (padded)
    __shared__ float mcol[NS];
    __shared__ float sX[NS][NWAY];

    const int t   = blockIdx.x;
    const int tid = threadIdx.x;
    const float* Sg = support + (size_t)t * NS * D;

    // Stage S into LDS (coalesced float4)
    for (int idx = tid; idx < NS * (D / 4); idx += 256) {
        int s  = idx / (D / 4);
        int d4 = idx % (D / 4);
        float4 v = reinterpret_cast<const float4*>(Sg)[idx];
        *reinterpret_cast<float4*>(&sS[s * SP + 4 * d4]) = v;
    }
    // RHS init: aug[s][NS+w] = 2 * onehot
    if (tid < NS * NWAY) {
        int s = tid / NWAY, w = tid % NWAY;
        aug[s][NS + w] = (labels[t * NS + s] == w) ? 2.0f : 0.0f;
    }
    __syncthreads();

    // K = S S^T + lambda I  (upper triangle, mirrored)
    for (int pp = tid; pp < NS * (NS + 1) / 2; pp += 256) {
        int p = pp, i = 0;
        while (p >= NS - i) { p -= NS - i; ++i; }
        int j = i + p;
        const float4* ri = reinterpret_cast<const float4*>(&sS[i * SP]);
        const float4* rj = reinterpret_cast<const float4*>(&sS[j * SP]);
        float acc = 0.0f;
        #pragma unroll 8
        for (int d4 = 0; d4 < D / 4; ++d4) {
            float4 a = ri[d4], b = rj[d4];
            acc += a.x * b.x + a.y * b.y + a.z * b.z + a.w * b.w;
        }
        if (i == j) acc += LAMBDA_REG;
        aug[i][j] = acc;
        aug[j][i] = acc;
    }
    __syncthreads();

    // Gauss-Jordan elimination (SPD -> no pivoting needed)
    for (int k = 0; k < NS; ++k) {
        if (tid < NS) mcol[tid] = aug[tid][k] / aug[k][k];
        __syncthreads();
        for (int idx = tid; idx < NS * AC; idx += 256) {
            int r = idx / AC, c = idx % AC;
            if (r != k) aug[r][c] -= mcol[r] * aug[k][c];
        }
        __syncthreads();
    }
    // X[s][w] = rhs / diag
    if (tid < NS * NWAY) {
        int s = tid / NWAY, w = tid % NWAY;
        sX[s][w] = aug[s][NS + w] / aug[s][s];
    }
    __syncthreads();

    // Wmat[t][w][d] = sum_s S[s][d] * X[s][w]  (coalesced per-w writes)
    for (int d = tid; d < D; d += 256) {
        float acc[NWAY] = {};
        #pragma unroll
        for (int s = 0; s < NS; ++s) {
            float sv = sS[s * SP + d];
            #pragma unroll
            for (int w = 0; w < NWAY; ++w) acc[w] += sv * sX[s][w];
        }
        #pragma unroll
        for (int w = 0; w < NWAY; ++w)
            wmat[((size_t)t * NWAY + w) * D + d] = acc[w];
    }
}

// ---------------------------------------------------------------------------
// Kernel 2: logits[t][q][w] = scale * sum_d Q[t][q][d] * Wmat[t][w][d]
// 16 lanes per query row; Wmat staged in LDS; shfl_xor reduction.
// ---------------------------------------------------------------------------
__global__ __launch_bounds__(256) void logits_kernel(
    const float* __restrict__ query,   // (T, NQ, D)
    const float* __restrict__ wmat,    // (T, NWAY, D)
    const float* __restrict__ scale,   // (1,)
    float*       __restrict__ out)     // (T, NQ, NWAY)
{
    __shared__ __align__(16) float sW[NWAY][D];   // 12,800 B

    const int b     = blockIdx.x;
    const int t     = b / CHUNKS;
    const int chunk = b % CHUNKS;
    const int tid   = threadIdx.x;

    for (int idx = tid; idx < NWAY * D / 4; idx += 256) {
        reinterpret_cast<float4*>(&sW[0][0])[idx] =
            reinterpret_cast<const float4*>(wmat + (size_t)t * NWAY * D)[idx];
    }
    __syncthreads();

    const float sc = scale[0];
    const int g = tid >> 4;   // group (query) 0..15
    const int l = tid & 15;   // lane in group

    #pragma unroll
    for (int j = 0; j < (QPB + 15) / 16; ++j) {
        int ql = j * 16 + g;          // 0..63
        if (ql < QPB) {               // wave-uniform skip for ql 60..63
            int q = chunk * QPB + ql; // < 300 exactly
            const float4* Qp =
                reinterpret_cast<const float4*>(query + ((size_t)t * NQ + q) * D);
            float acc[NWAY] = {};
            #pragma unroll
            for (int i = 0; i < D / 64; ++i) {   // 10 iterations
                float4 v = Qp[i * 16 + l];
                int d = i * 64 + l * 4;
                #pragma unroll
                for (int w = 0; w < NWAY; ++w) {
                    float4 wv = *reinterpret_cast<const float4*>(&sW[w][d]);
                    acc[w] += v.x * wv.x + v.y * wv.y + v.z * wv.z + v.w * wv.w;
                }
            }
            // reduce across the 16-lane group (xor masks stay in-group)
            #pragma unroll
            for (int off = 8; off >= 1; off >>= 1) {
                #pragma unroll
                for (int w = 0; w < NWAY; ++w)
                    acc[w] += __shfl_xor(acc[w], off);
            }
            if (l == 0) {
                float* o = out + ((size_t)t * NQ + q) * NWAY;
                #pragma unroll
                for (int w = 0; w < NWAY; ++w) o[w] = sc * acc[w];
            }
        }
    }
}

extern "C" void kernel_launch(void* const* d_in, const int* in_sizes, int n_in,
                              void* d_out, int out_size, void* d_ws, size_t ws_size,
                              hipStream_t stream) {
    const float* query   = (const float*)d_in[0];
    const float* support = (const float*)d_in[1];
    const float* scale   = (const float*)d_in[2];
    const int*   labels  = (const int*)d_in[3];

    float* wmat = (float*)d_ws;          // needs T*NWAY*D*4 = 3,276,800 B
    float* out  = (float*)d_out;

    ridge_solve_kernel<<<T_TASKS, 256, 0, stream>>>(support, labels, wmat);
    logits_kernel<<<T_TASKS * CHUNKS, 256, 0, stream>>>(query, wmat, scale, out);
}

// Round 2
// 47.966 us; speedup vs baseline: 1.3344x; 1.3344x over previous
//
#include <hip/hip_runtime.h>

// Problem constants (fixed by setup_inputs)
constexpr int T_TASKS = 256;
constexpr int NQ      = 300;
constexpr int NS      = 25;
constexpr int D       = 640;
constexpr int NWAY    = 5;
constexpr float LAMBDA_REG = 50.0f;

constexpr int SP4 = 161;   // float4 stride of one S row in LDS (644 floats)
constexpr int NT  = 1024;  // threads per block (16 waves)
constexpr int AC  = NS + NWAY;  // augmented columns = 30

// Pair-block table: 15 upper-triangle 5x5 blocks of the 25x25 Gram matrix
__device__ __constant__ int PA[15] = {0,0,0,0,0,1,1,1,1,2,2,2,3,3,4};
__device__ __constant__ int PB[15] = {0,1,2,3,4,1,2,3,4,2,3,4,3,4,4};

// ---------------------------------------------------------------------------
// Fused: per-task ridge solve (K = S S^T + lambda I, X = 2 K^{-1} Y,
// W = S^T X) followed by logits = scale * Q W. One block per task.
// ---------------------------------------------------------------------------
__global__ __launch_bounds__(NT) void fused_ridge_head_kernel(
    const float* __restrict__ query,    // (T, NQ, D)
    const float* __restrict__ support,  // (T, NS, D)
    const float* __restrict__ scale,    // (1,)
    const int*   __restrict__ labels,   // (T, NS)
    float*       __restrict__ out)      // (T, NQ, NWAY)
{
    __shared__ __align__(16) float4 sS4[NS * SP4];   // 64,400 B
    __shared__ __align__(16) float  sW[NWAY][D];     // 12,800 B
    __shared__ float aug[NS][32];                    //  3,200 B
    __shared__ float sX[NS][NWAY];                   //    500 B

    const int t   = blockIdx.x;
    const int tid = threadIdx.x;
    const float* Sg    = support + (size_t)t * NS * D;
    const float* Qbase = query   + (size_t)t * NQ * D;

    // ---- Phase A1: stage S into LDS (coalesced float4) + RHS init ----------
    for (int idx = tid; idx < NS * 160; idx += NT) {
        int s = idx / 160, f = idx % 160;
        sS4[s * SP4 + f] = reinterpret_cast<const float4*>(Sg)[idx];
    }
    if (tid >= 960) {                       // wave 15: RHS = 2 * onehot
        for (int idx = tid - 960; idx < NS * NWAY; idx += 64) {
            int s = idx / NWAY, w = idx % NWAY;
            aug[s][NS + w] = (labels[t * NS + s] == w) ? 2.0f : 0.0f;
        }
    }
    __syncthreads();

    // ---- Phase A2: K = S S^T + lambda I, 5x5 register-blocked --------------
    // 15 groups of 16 lanes (waves 0..3). Each group: one 5x5 pair-block.
    if (tid < 240) {
        const int grp = tid >> 4, l = tid & 15;
        const int ra = PA[grp] * 5, rb = PB[grp] * 5;
        float acc[25] = {};
        #pragma unroll
        for (int k = 0; k < 10; ++k) {      // lane's float4 slice: f = l + 16k
            const int f = l + 16 * k;
            float4 A[5], B[5];
            #pragma unroll
            for (int r = 0; r < 5; ++r) A[r] = sS4[(ra + r) * SP4 + f];
            #pragma unroll
            for (int r = 0; r < 5; ++r) B[r] = sS4[(rb + r) * SP4 + f];
            #pragma unroll
            for (int i = 0; i < 5; ++i)
                #pragma unroll
                for (int j = 0; j < 5; ++j)
                    acc[i * 5 + j] += A[i].x * B[j].x + A[i].y * B[j].y +
                                      A[i].z * B[j].z + A[i].w * B[j].w;
        }
        #pragma unroll
        for (int p = 0; p < 25; ++p) {      // reduce across the 16-lane group
            #pragma unroll
            for (int off = 8; off >= 1; off >>= 1)
                acc[p] += __shfl_xor(acc[p], off);
        }
        if (l == 0) {
            #pragma unroll
            for (int p = 0; p < 25; ++p) {
                int i = ra + p / 5, j = rb + p % 5;
                float v = acc[p] + (i == j ? LAMBDA_REG : 0.0f);
                aug[i][j] = v;
                aug[j][i] = v;
            }
        }
    }
    __syncthreads();

    // ---- Prefetch: issue first 2 float4 of each group's round-0 Q row ------
    const int g  = tid >> 4;      // 64 groups of 16 lanes
    const int l4 = tid & 15;
    const float4* Qp0 = reinterpret_cast<const float4*>(Qbase + (size_t)g * D);
    float4 pf0 = Qp0[l4];
    float4 pf1 = Qp0[16 + l4];

    // ---- Phase A3: Gauss-Jordan in wave-0 registers (no barriers) ----------
    // Lane c holds column c of the 25x30 augmented system.
    if (tid < 64) {
        const int  c      = tid;
        const bool active = (c < AC);
        float a[NS];
        #pragma unroll
        for (int r = 0; r < NS; ++r) a[r] = active ? aug[r][c] : 0.0f;
        #pragma unroll
        for (int k = 0; k < NS; ++k) {
            float piv = __shfl(a[k], k);    // aug[k][k]
            float inv = 1.0f / piv;
            a[k] *= inv;                    // scale row k (all columns)
            #pragma unroll
            for (int r = 0; r < NS; ++r) {
                if (r != k) {
                    float m = __shfl(a[r], k);   // aug[r][k]
                    a[r] -= m * a[k];
                }
            }
        }
        if (active && c >= NS) {            // RHS columns now hold X = 2 K^-1 Y
            const int w = c - NS;
            #pragma unroll
            for (int s = 0; s < NS; ++s) sX[s][w] = a[s];
        }
    }
    __syncthreads();

    // ---- Phase A4: W[w][d] = sum_s S[s][d] * X[s][w] -----------------------
    if (tid < D) {
        const float* sSf = reinterpret_cast<const float*>(sS4);
        float acc[NWAY] = {};
        #pragma unroll
        for (int s = 0; s < NS; ++s) {
            float sv = sSf[s * (SP4 * 4) + tid];
            #pragma unroll
            for (int w = 0; w < NWAY; ++w) acc[w] += sv * sX[s][w];
        }
        #pragma unroll
        for (int w = 0; w < NWAY; ++w) sW[w][tid] = acc[w];
    }
    __syncthreads();

    // ---- Phase B: logits = scale * Q W  (16 lanes per query row) -----------
    const float sc = scale[0];

    auto fma_step = [&](float acc[NWAY], float4 v, int i) {
        const int dbase = i * 64 + 4 * l4;
        #pragma unroll
        for (int w = 0; w < NWAY; ++w) {
            const float4 wv = *reinterpret_cast<const float4*>(&sW[w][dbase]);
            acc[w] += v.x * wv.x + v.y * wv.y + v.z * wv.z + v.w * wv.w;
        }
    };
    auto reduce_store = [&](float acc[NWAY], int q) {
        #pragma unroll
        for (int w = 0; w < NWAY; ++w) {
            #pragma unroll
            for (int off = 8; off >= 1; off >>= 1)
                acc[w] += __shfl_xor(acc[w], off);
        }
        if (l4 == 0) {
            float* o = out + ((size_t)t * NQ + q) * NWAY;
            #pragma unroll
            for (int w = 0; w < NWAY; ++w) o[w] = sc * acc[w];
        }
    };

    {   // round 0: q = g, first two float4 already in flight
        float acc[NWAY] = {};
        fma_step(acc, pf0, 0);
        fma_step(acc, pf1, 1);
        #pragma unroll
        for (int i = 2; i < 10; ++i) fma_step(acc, Qp0[i * 16 + l4], i);
        reduce_store(acc, g);
    }
    #pragma unroll
    for (int j = 1; j < 5; ++j) {
        const int q = j * 64 + g;
        if (q < NQ) {
            const float4* Qp = reinterpret_cast<const float4*>(Qbase + (size_t)q * D);
            float acc[NWAY] = {};
            #pragma unroll
            for (int i = 0; i < 10; ++i) fma_step(acc, Qp[i * 16 + l4], i);
            reduce_store(acc, q);
        }
    }
}

extern "C" void kernel_launch(void* const* d_in, const int* in_sizes, int n_in,
                              void* d_out, int out_size, void* d_ws, size_t ws_size,
                              hipStream_t stream) {
    const float* query   = (const float*)d_in[0];
    const float* support = (const float*)d_in[1];
    const float* scale   = (const float*)d_in[2];
    const int*   labels  = (const int*)d_in[3];
    float* out = (float*)d_out;

    fused_ridge_head_kernel<<<T_TASKS, NT, 0, stream>>>(query, support, scale, labels, out);
}